// Round 3
// baseline (92.817 us; speedup 1.0000x reference)
//
#include <hip/hip_runtime.h>

#define NQ 8
#define NLAYERS 3

typedef unsigned int uint2ev __attribute__((ext_vector_type(2)));

// ---- cross-lane xor exchange, off the DS pipe where possible ----
template<int MASK>
__device__ __forceinline__ float xorlane(float v, int lane) {
    if constexpr (MASK == 1) {
        return __int_as_float(__builtin_amdgcn_mov_dpp(__float_as_int(v), 0xB1, 0xF, 0xF, false)); // quad_perm [1,0,3,2]
    } else if constexpr (MASK == 2) {
        return __int_as_float(__builtin_amdgcn_mov_dpp(__float_as_int(v), 0x4E, 0xF, 0xF, false)); // quad_perm [2,3,0,1]
    } else if constexpr (MASK == 8) {
        return __int_as_float(__builtin_amdgcn_mov_dpp(__float_as_int(v), 0x128, 0xF, 0xF, false)); // row_ror:8 == xor 8
    }
#if __has_builtin(__builtin_amdgcn_permlane16_swap)
    else if constexpr (MASK == 16) {
        uint2ev r = __builtin_amdgcn_permlane16_swap(__float_as_uint(v), __float_as_uint(v), false, false);
        return __uint_as_float((lane & 16) ? r.x : r.y);
    }
#endif
#if __has_builtin(__builtin_amdgcn_permlane32_swap)
    else if constexpr (MASK == 32) {
        uint2ev r = __builtin_amdgcn_permlane32_swap(__float_as_uint(v), __float_as_uint(v), false, false);
        return __uint_as_float((lane & 32) ? r.x : r.y);
    }
#endif
    else {
        return __shfl_xor(v, MASK);
    }
}

__device__ __forceinline__ void ry_pair(float c, float s, float& a0, float& a1) {
    float n0 = c * a0 - s * a1;
    float n1 = s * a0 + c * a1;
    a0 = n0; a1 = n1;
}

template<int Q>
__device__ __forceinline__ void apply_ry_t(float c, float s, float ar[4], float ai[4], int lane) {
    if constexpr (Q == 0) {
        ry_pair(c, s, ar[0], ar[1]); ry_pair(c, s, ai[0], ai[1]);
        ry_pair(c, s, ar[2], ar[3]); ry_pair(c, s, ai[2], ai[3]);
    } else if constexpr (Q == 1) {
        ry_pair(c, s, ar[0], ar[2]); ry_pair(c, s, ai[0], ai[2]);
        ry_pair(c, s, ar[1], ar[3]); ry_pair(c, s, ai[1], ai[3]);
    } else {
        constexpr int mask = 1 << (Q - 2);
        float sgn = (lane & mask) ? s : -s;
#pragma unroll
        for (int j = 0; j < 4; ++j) {
            float pr = xorlane<mask>(ar[j], lane);
            float pq = xorlane<mask>(ai[j], lane);
            ar[j] = c * ar[j] + sgn * pr;
            ai[j] = c * ai[j] + sgn * pq;
        }
    }
}

__device__ __forceinline__ void rz_amp(float cp, float ssp, float& r, float& i) {
    float nr = r * cp - i * ssp;
    float ni = i * cp + r * ssp;
    r = nr; i = ni;
}

template<int Q>
__device__ __forceinline__ void apply_rz_t(float cp, float sp, float ar[4], float ai[4], int lane) {
    if constexpr (Q == 0) {
        rz_amp(cp, -sp, ar[0], ai[0]); rz_amp(cp,  sp, ar[1], ai[1]);
        rz_amp(cp, -sp, ar[2], ai[2]); rz_amp(cp,  sp, ar[3], ai[3]);
    } else if constexpr (Q == 1) {
        rz_amp(cp, -sp, ar[0], ai[0]); rz_amp(cp, -sp, ar[1], ai[1]);
        rz_amp(cp,  sp, ar[2], ai[2]); rz_amp(cp,  sp, ar[3], ai[3]);
    } else {
        float ssp = (lane & (1 << (Q - 2))) ? sp : -sp;
#pragma unroll
        for (int j = 0; j < 4; ++j) rz_amp(cp, ssp, ar[j], ai[j]);
    }
}

// CNOT(c, (c+1)%8)
template<int C>
__device__ __forceinline__ void apply_cnot_t(float ar[4], float ai[4], int lane) {
    if constexpr (C == 0) {
        float t;
        t = ar[1]; ar[1] = ar[3]; ar[3] = t;
        t = ai[1]; ai[1] = ai[3]; ai[3] = t;
    } else if constexpr (C == 1) {
        ar[2] = xorlane<1>(ar[2], lane); ai[2] = xorlane<1>(ai[2], lane);
        ar[3] = xorlane<1>(ar[3], lane); ai[3] = xorlane<1>(ai[3], lane);
    } else if constexpr (C == 7) {
        bool hi = (lane & 32) != 0;
        float t0 = ar[0]; ar[0] = hi ? ar[1] : ar[0]; ar[1] = hi ? t0 : ar[1];
        float u0 = ai[0]; ai[0] = hi ? ai[1] : ai[0]; ai[1] = hi ? u0 : ai[1];
        float t2 = ar[2]; ar[2] = hi ? ar[3] : ar[2]; ar[3] = hi ? t2 : ar[3];
        float u2 = ai[2]; ai[2] = hi ? ai[3] : ai[2]; ai[3] = hi ? u2 : ai[3];
    } else {
        constexpr int cm = 1 << (C - 2);
        constexpr int tm = 1 << (C - 1);
        bool hi = (lane & cm) != 0;
#pragma unroll
        for (int j = 0; j < 4; ++j) {
            float pr = xorlane<tm>(ar[j], lane);
            float pq = xorlane<tm>(ai[j], lane);
            ar[j] = hi ? pr : ar[j];
            ai[j] = hi ? pq : ai[j];
        }
    }
}

template<int M>
__device__ __forceinline__ void reduce_z(float z[8], int lane) {
#pragma unroll
    for (int q = 0; q < 8; ++q) z[q] += xorlane<M>(z[q], lane);
}

// ============ Kernel A: quantum circuit -> z[B][8] ============
__global__ __launch_bounds__(256) void qcircuit_z(
    const float* __restrict__ x,        // [B,8]
    const float* __restrict__ qw,       // [3,8,2]
    float* __restrict__ zws,            // [B,8]
    int B)
{
    __shared__ float4 tab[NLAYERS * NQ];

    int tid = threadIdx.x;
    if (tid < NLAYERS * NQ) {
        float w0 = 0.5f * qw[tid * 2 + 0];
        float w1 = 0.5f * qw[tid * 2 + 1];
        tab[tid] = make_float4(__cosf(w0), __sinf(w0), __cosf(w1), __sinf(w1));
    }
    __syncthreads();

    int lane = tid & 63;
    int wid  = tid >> 6;
    int sample = blockIdx.x * 4 + wid;
    if (sample >= B) return;

    const float4* x4 = (const float4*)(x + sample * 8);
    float4 xa = x4[0], xb = x4[1];
    float xs[8] = {xa.x, xa.y, xa.z, xa.w, xb.x, xb.y, xb.z, xb.w};
    float xmin = xs[0], xmax = xs[0];
#pragma unroll
    for (int q = 1; q < 8; ++q) {
        xmin = fminf(xmin, xs[q]);
        xmax = fmaxf(xmax, xs[q]);
    }
    float inv = 1.0f / (xmax - xmin + 1e-8f);

    // encoding: product state directly
    float cq[8], sq[8];
#pragma unroll
    for (int q = 0; q < 8; ++q) {
        float a = (xs[q] - xmin) * inv * 1.5707963267948966f;
        cq[q] = __cosf(a);
        sq[q] = __sinf(a);
    }
    float pl = 1.0f;
#pragma unroll
    for (int q = 2; q < 8; ++q) pl *= ((lane >> (q - 2)) & 1) ? sq[q] : cq[q];

    float ar[4], ai[4];
    ar[0] = pl * cq[0] * cq[1];
    ar[1] = pl * sq[0] * cq[1];
    ar[2] = pl * cq[0] * sq[1];
    ar[3] = pl * sq[0] * sq[1];
    ai[0] = 0.f; ai[1] = 0.f; ai[2] = 0.f; ai[3] = 0.f;

#pragma unroll
    for (int l = 0; l < NLAYERS; ++l) {
        const float4* tl = &tab[l * NQ];
        float4 t;
        t = tl[0]; apply_ry_t<0>(t.x, t.y, ar, ai, lane); apply_rz_t<0>(t.z, t.w, ar, ai, lane);
        t = tl[1]; apply_ry_t<1>(t.x, t.y, ar, ai, lane); apply_rz_t<1>(t.z, t.w, ar, ai, lane);
        t = tl[2]; apply_ry_t<2>(t.x, t.y, ar, ai, lane); apply_rz_t<2>(t.z, t.w, ar, ai, lane);
        t = tl[3]; apply_ry_t<3>(t.x, t.y, ar, ai, lane); apply_rz_t<3>(t.z, t.w, ar, ai, lane);
        t = tl[4]; apply_ry_t<4>(t.x, t.y, ar, ai, lane); apply_rz_t<4>(t.z, t.w, ar, ai, lane);
        t = tl[5]; apply_ry_t<5>(t.x, t.y, ar, ai, lane); apply_rz_t<5>(t.z, t.w, ar, ai, lane);
        t = tl[6]; apply_ry_t<6>(t.x, t.y, ar, ai, lane); apply_rz_t<6>(t.z, t.w, ar, ai, lane);
        t = tl[7]; apply_ry_t<7>(t.x, t.y, ar, ai, lane); apply_rz_t<7>(t.z, t.w, ar, ai, lane);
        apply_cnot_t<0>(ar, ai, lane);
        apply_cnot_t<1>(ar, ai, lane);
        apply_cnot_t<2>(ar, ai, lane);
        apply_cnot_t<3>(ar, ai, lane);
        apply_cnot_t<4>(ar, ai, lane);
        apply_cnot_t<5>(ar, ai, lane);
        apply_cnot_t<6>(ar, ai, lane);
        apply_cnot_t<7>(ar, ai, lane);
    }

    float p[4];
#pragma unroll
    for (int j = 0; j < 4; ++j) p[j] = ar[j] * ar[j] + ai[j] * ai[j];

    float z[8];
    z[0] = (p[0] - p[1]) + (p[2] - p[3]);
    z[1] = (p[0] + p[1]) - (p[2] + p[3]);
    float sall = (p[0] + p[1]) + (p[2] + p[3]);
#pragma unroll
    for (int q = 2; q < 8; ++q)
        z[q] = (lane & (1 << (q - 2))) ? -sall : sall;

    reduce_z<1>(z, lane);
    reduce_z<2>(z, lane);
    reduce_z<4>(z, lane);
    reduce_z<8>(z, lane);
    reduce_z<16>(z, lane);
    reduce_z<32>(z, lane);

    if (lane == 0) {
        *(float4*)(zws + sample * 8)     = make_float4(z[0], z[1], z[2], z[3]);
        *(float4*)(zws + sample * 8 + 4) = make_float4(z[4], z[5], z[6], z[7]);
    }
}

// ============ Kernel B: z -> out (register-blocked MLP) ============
// block = 256 threads, 32 samples. Each thread: 4 output cols x 8 samples,
// W2 float4 registers reused 8x.
__global__ __launch_bounds__(256) void qmlp2(
    const float* __restrict__ zws,      // [B,8]
    const float* __restrict__ W1,       // [8,64]
    const float* __restrict__ b1,       // [64]
    const float* __restrict__ W2,       // [64,256]
    const float* __restrict__ b2,       // [256]
    float* __restrict__ out,            // [B,256]
    int B)
{
    __shared__ float h_lds[32][64];

    int t = threadIdx.x;
    int s0 = blockIdx.x * 32;

    // phase 1: h tile
    {
        int s_l = t >> 3;               // 0..31
        int i_l = (t & 7) * 8;          // 0,8,...,56
        int srow = s0 + s_l; if (srow >= B) srow = B - 1;
        const float* zr = zws + srow * 8;
        float4 za = *(const float4*)zr;
        float4 zb = *(const float4*)(zr + 4);
        float zq[8] = {za.x, za.y, za.z, za.w, zb.x, zb.y, zb.z, zb.w};
        float4 acc0 = *(const float4*)(b1 + i_l);
        float4 acc1 = *(const float4*)(b1 + i_l + 4);
#pragma unroll
        for (int q = 0; q < 8; ++q) {
            float4 w0 = *(const float4*)(W1 + q * 64 + i_l);
            float4 w1 = *(const float4*)(W1 + q * 64 + i_l + 4);
            acc0.x += zq[q] * w0.x; acc0.y += zq[q] * w0.y;
            acc0.z += zq[q] * w0.z; acc0.w += zq[q] * w0.w;
            acc1.x += zq[q] * w1.x; acc1.y += zq[q] * w1.y;
            acc1.z += zq[q] * w1.z; acc1.w += zq[q] * w1.w;
        }
        acc0.x = fmaxf(acc0.x, 0.f); acc0.y = fmaxf(acc0.y, 0.f);
        acc0.z = fmaxf(acc0.z, 0.f); acc0.w = fmaxf(acc0.w, 0.f);
        acc1.x = fmaxf(acc1.x, 0.f); acc1.y = fmaxf(acc1.y, 0.f);
        acc1.z = fmaxf(acc1.z, 0.f); acc1.w = fmaxf(acc1.w, 0.f);
        *(float4*)&h_lds[s_l][i_l]     = acc0;
        *(float4*)&h_lds[s_l][i_l + 4] = acc1;
    }
    __syncthreads();

    // phase 2: out = h @ W2 + b2
    int sgrp = t >> 6;                  // 0..3 -> samples sgrp*8 .. +7
    int c4 = (t & 63) * 4;
    float4 bb = *(const float4*)(b2 + c4);
    float4 acc[8];
#pragma unroll
    for (int s = 0; s < 8; ++s) acc[s] = bb;

#pragma unroll
    for (int i4 = 0; i4 < 16; ++i4) {
        float4 w0 = *(const float4*)(W2 + (i4 * 4 + 0) * 256 + c4);
        float4 w1 = *(const float4*)(W2 + (i4 * 4 + 1) * 256 + c4);
        float4 w2 = *(const float4*)(W2 + (i4 * 4 + 2) * 256 + c4);
        float4 w3 = *(const float4*)(W2 + (i4 * 4 + 3) * 256 + c4);
#pragma unroll
        for (int s = 0; s < 8; ++s) {
            float4 h4 = *(const float4*)&h_lds[sgrp * 8 + s][i4 * 4];
            acc[s].x += h4.x * w0.x + h4.y * w1.x + h4.z * w2.x + h4.w * w3.x;
            acc[s].y += h4.x * w0.y + h4.y * w1.y + h4.z * w2.y + h4.w * w3.y;
            acc[s].z += h4.x * w0.z + h4.y * w1.z + h4.z * w2.z + h4.w * w3.z;
            acc[s].w += h4.x * w0.w + h4.y * w1.w + h4.z * w2.w + h4.w * w3.w;
        }
    }

#pragma unroll
    for (int s = 0; s < 8; ++s) {
        int srow = s0 + sgrp * 8 + s;
        if (srow < B)
            *(float4*)(out + srow * 256 + c4) = acc[s];
    }
}

extern "C" void kernel_launch(void* const* d_in, const int* in_sizes, int n_in,
                              void* d_out, int out_size, void* d_ws, size_t ws_size,
                              hipStream_t stream) {
    const float* x  = (const float*)d_in[0];
    const float* qw = (const float*)d_in[1];
    const float* W1 = (const float*)d_in[2];
    const float* b1 = (const float*)d_in[3];
    const float* W2 = (const float*)d_in[4];
    const float* b2 = (const float*)d_in[5];
    float* out = (float*)d_out;
    float* zws = (float*)d_ws;          // needs B*8*4 = 256 KiB

    int B = in_sizes[0] / NQ;           // 8192

    qcircuit_z<<<(B + 3) / 4, 256, 0, stream>>>(x, qw, zws, B);
    qmlp2<<<(B + 31) / 32, 256, 0, stream>>>(zws, W1, b1, W2, b2, out, B);
}

// Round 4
// 37.365 us; speedup vs baseline: 2.4840x; 2.4840x over previous
//
#include <hip/hip_runtime.h>

#define NQ 8
#define NLAYERS 3

typedef unsigned int uint2ev __attribute__((ext_vector_type(2)));

// ---- cross-lane xor exchange, off the DS pipe where possible ----
template<int MASK>
__device__ __forceinline__ float xorlane(float v, int lane) {
    if constexpr (MASK == 1) {
        return __int_as_float(__builtin_amdgcn_mov_dpp(__float_as_int(v), 0xB1, 0xF, 0xF, false)); // quad_perm [1,0,3,2]
    } else if constexpr (MASK == 2) {
        return __int_as_float(__builtin_amdgcn_mov_dpp(__float_as_int(v), 0x4E, 0xF, 0xF, false)); // quad_perm [2,3,0,1]
    } else if constexpr (MASK == 8) {
        return __int_as_float(__builtin_amdgcn_mov_dpp(__float_as_int(v), 0x128, 0xF, 0xF, false)); // row_ror:8 == xor 8
    }
#if __has_builtin(__builtin_amdgcn_permlane16_swap)
    else if constexpr (MASK == 16) {
        uint2ev r = __builtin_amdgcn_permlane16_swap(__float_as_uint(v), __float_as_uint(v), false, false);
        return __uint_as_float((lane & 16) ? r.x : r.y);
    }
#endif
#if __has_builtin(__builtin_amdgcn_permlane32_swap)
    else if constexpr (MASK == 32) {
        uint2ev r = __builtin_amdgcn_permlane32_swap(__float_as_uint(v), __float_as_uint(v), false, false);
        return __uint_as_float((lane & 32) ? r.x : r.y);
    }
#endif
    else {
        return __shfl_xor(v, MASK);
    }
}

struct QS { float ar[4]; float ai[4]; };

__device__ __forceinline__ void ry_pair(float c, float s, float& a0, float& a1) {
    float n0 = c * a0 - s * a1;
    float n1 = s * a0 + c * a1;
    a0 = n0; a1 = n1;
}

template<int Q>
__device__ __forceinline__ void apply_ry_t(float c, float s, QS& st, int lane) {
    if constexpr (Q == 0) {
        ry_pair(c, s, st.ar[0], st.ar[1]); ry_pair(c, s, st.ai[0], st.ai[1]);
        ry_pair(c, s, st.ar[2], st.ar[3]); ry_pair(c, s, st.ai[2], st.ai[3]);
    } else if constexpr (Q == 1) {
        ry_pair(c, s, st.ar[0], st.ar[2]); ry_pair(c, s, st.ai[0], st.ai[2]);
        ry_pair(c, s, st.ar[1], st.ar[3]); ry_pair(c, s, st.ai[1], st.ai[3]);
    } else {
        constexpr int mask = 1 << (Q - 2);
        float sgn = (lane & mask) ? s : -s;
#pragma unroll
        for (int j = 0; j < 4; ++j) {
            float pr = xorlane<mask>(st.ar[j], lane);
            float pq = xorlane<mask>(st.ai[j], lane);
            st.ar[j] = c * st.ar[j] + sgn * pr;
            st.ai[j] = c * st.ai[j] + sgn * pq;
        }
    }
}

__device__ __forceinline__ void rz_amp(float cp, float ssp, float& r, float& i) {
    float nr = r * cp - i * ssp;
    float ni = i * cp + r * ssp;
    r = nr; i = ni;
}

template<int Q>
__device__ __forceinline__ void apply_rz_t(float cp, float sp, QS& st, int lane) {
    if constexpr (Q == 0) {
        rz_amp(cp, -sp, st.ar[0], st.ai[0]); rz_amp(cp,  sp, st.ar[1], st.ai[1]);
        rz_amp(cp, -sp, st.ar[2], st.ai[2]); rz_amp(cp,  sp, st.ar[3], st.ai[3]);
    } else if constexpr (Q == 1) {
        rz_amp(cp, -sp, st.ar[0], st.ai[0]); rz_amp(cp, -sp, st.ar[1], st.ai[1]);
        rz_amp(cp,  sp, st.ar[2], st.ai[2]); rz_amp(cp,  sp, st.ar[3], st.ai[3]);
    } else {
        float ssp = (lane & (1 << (Q - 2))) ? sp : -sp;
#pragma unroll
        for (int j = 0; j < 4; ++j) rz_amp(cp, ssp, st.ar[j], st.ai[j]);
    }
}

// CNOT(c, (c+1)%8)
template<int C>
__device__ __forceinline__ void apply_cnot_t(QS& st, int lane) {
    if constexpr (C == 0) {
        float t;
        t = st.ar[1]; st.ar[1] = st.ar[3]; st.ar[3] = t;
        t = st.ai[1]; st.ai[1] = st.ai[3]; st.ai[3] = t;
    } else if constexpr (C == 1) {
        st.ar[2] = xorlane<1>(st.ar[2], lane); st.ai[2] = xorlane<1>(st.ai[2], lane);
        st.ar[3] = xorlane<1>(st.ar[3], lane); st.ai[3] = xorlane<1>(st.ai[3], lane);
    } else if constexpr (C == 7) {
        bool hi = (lane & 32) != 0;
        float t0 = st.ar[0]; st.ar[0] = hi ? st.ar[1] : st.ar[0]; st.ar[1] = hi ? t0 : st.ar[1];
        float u0 = st.ai[0]; st.ai[0] = hi ? st.ai[1] : st.ai[0]; st.ai[1] = hi ? u0 : st.ai[1];
        float t2 = st.ar[2]; st.ar[2] = hi ? st.ar[3] : st.ar[2]; st.ar[3] = hi ? t2 : st.ar[3];
        float u2 = st.ai[2]; st.ai[2] = hi ? st.ai[3] : st.ai[2]; st.ai[3] = hi ? u2 : st.ai[3];
    } else {
        constexpr int cm = 1 << (C - 2);
        constexpr int tm = 1 << (C - 1);
        bool hi = (lane & cm) != 0;
#pragma unroll
        for (int j = 0; j < 4; ++j) {
            float pr = xorlane<tm>(st.ar[j], lane);
            float pq = xorlane<tm>(st.ai[j], lane);
            st.ar[j] = hi ? pr : st.ar[j];
            st.ai[j] = hi ? pq : st.ai[j];
        }
    }
}

template<int M>
__device__ __forceinline__ void reduce_z(float z[8], int lane) {
#pragma unroll
    for (int q = 0; q < 8; ++q) z[q] += xorlane<M>(z[q], lane);
}

__device__ __forceinline__ void encode_state(const float* __restrict__ x, int sample,
                                             int lane, QS& st) {
    const float4* x4 = (const float4*)(x + sample * 8);
    float4 xa = x4[0], xb = x4[1];
    float xs[8] = {xa.x, xa.y, xa.z, xa.w, xb.x, xb.y, xb.z, xb.w};
    float xmin = xs[0], xmax = xs[0];
#pragma unroll
    for (int q = 1; q < 8; ++q) {
        xmin = fminf(xmin, xs[q]);
        xmax = fmaxf(xmax, xs[q]);
    }
    float inv = 1.0f / (xmax - xmin + 1e-8f);
    float cq[8], sq[8];
#pragma unroll
    for (int q = 0; q < 8; ++q) {
        float a = (xs[q] - xmin) * inv * 1.5707963267948966f;
        cq[q] = __cosf(a);
        sq[q] = __sinf(a);
    }
    float pl = 1.0f;
#pragma unroll
    for (int q = 2; q < 8; ++q) pl *= ((lane >> (q - 2)) & 1) ? sq[q] : cq[q];
    st.ar[0] = pl * cq[0] * cq[1];
    st.ar[1] = pl * sq[0] * cq[1];
    st.ar[2] = pl * cq[0] * sq[1];
    st.ar[3] = pl * sq[0] * sq[1];
    st.ai[0] = 0.f; st.ai[1] = 0.f; st.ai[2] = 0.f; st.ai[3] = 0.f;
}

__device__ __forceinline__ void measure_z(const QS& st, int lane, float z[8]) {
    float p[4];
#pragma unroll
    for (int j = 0; j < 4; ++j) p[j] = st.ar[j] * st.ar[j] + st.ai[j] * st.ai[j];
    z[0] = (p[0] - p[1]) + (p[2] - p[3]);
    z[1] = (p[0] + p[1]) - (p[2] + p[3]);
    float sall = (p[0] + p[1]) + (p[2] + p[3]);
#pragma unroll
    for (int q = 2; q < 8; ++q)
        z[q] = (lane & (1 << (q - 2))) ? -sall : sall;
    reduce_z<1>(z, lane);
    reduce_z<2>(z, lane);
    reduce_z<4>(z, lane);
    reduce_z<8>(z, lane);
    reduce_z<16>(z, lane);
    reduce_z<32>(z, lane);
}

// ============ Kernel A: quantum circuit, 2 samples per wave -> z[B][8] ============
__global__ __launch_bounds__(256) void qcircuit_z(
    const float* __restrict__ x,        // [B,8]
    const float* __restrict__ qw,       // [3,8,2]
    float* __restrict__ zws,            // [B,8]
    int B)
{
    __shared__ float4 tab[NLAYERS * NQ];

    int tid = threadIdx.x;
    if (tid < NLAYERS * NQ) {
        float w0 = 0.5f * qw[tid * 2 + 0];
        float w1 = 0.5f * qw[tid * 2 + 1];
        tab[tid] = make_float4(__cosf(w0), __sinf(w0), __cosf(w1), __sinf(w1));
    }
    __syncthreads();

    int lane = tid & 63;
    int wid  = tid >> 6;
    int s0 = (blockIdx.x * 4 + wid) * 2;
    if (s0 >= B) return;
    int s1 = (s0 + 1 < B) ? s0 + 1 : s0;

    QS A, Bs;
    encode_state(x, s0, lane, A);
    encode_state(x, s1, lane, Bs);

#pragma unroll
    for (int l = 0; l < NLAYERS; ++l) {
        const float4* tl = &tab[l * NQ];
        float4 t;
        t = tl[0]; apply_ry_t<0>(t.x, t.y, A, lane); apply_ry_t<0>(t.x, t.y, Bs, lane);
                   apply_rz_t<0>(t.z, t.w, A, lane); apply_rz_t<0>(t.z, t.w, Bs, lane);
        t = tl[1]; apply_ry_t<1>(t.x, t.y, A, lane); apply_ry_t<1>(t.x, t.y, Bs, lane);
                   apply_rz_t<1>(t.z, t.w, A, lane); apply_rz_t<1>(t.z, t.w, Bs, lane);
        t = tl[2]; apply_ry_t<2>(t.x, t.y, A, lane); apply_ry_t<2>(t.x, t.y, Bs, lane);
                   apply_rz_t<2>(t.z, t.w, A, lane); apply_rz_t<2>(t.z, t.w, Bs, lane);
        t = tl[3]; apply_ry_t<3>(t.x, t.y, A, lane); apply_ry_t<3>(t.x, t.y, Bs, lane);
                   apply_rz_t<3>(t.z, t.w, A, lane); apply_rz_t<3>(t.z, t.w, Bs, lane);
        t = tl[4]; apply_ry_t<4>(t.x, t.y, A, lane); apply_ry_t<4>(t.x, t.y, Bs, lane);
                   apply_rz_t<4>(t.z, t.w, A, lane); apply_rz_t<4>(t.z, t.w, Bs, lane);
        t = tl[5]; apply_ry_t<5>(t.x, t.y, A, lane); apply_ry_t<5>(t.x, t.y, Bs, lane);
                   apply_rz_t<5>(t.z, t.w, A, lane); apply_rz_t<5>(t.z, t.w, Bs, lane);
        t = tl[6]; apply_ry_t<6>(t.x, t.y, A, lane); apply_ry_t<6>(t.x, t.y, Bs, lane);
                   apply_rz_t<6>(t.z, t.w, A, lane); apply_rz_t<6>(t.z, t.w, Bs, lane);
        t = tl[7]; apply_ry_t<7>(t.x, t.y, A, lane); apply_ry_t<7>(t.x, t.y, Bs, lane);
                   apply_rz_t<7>(t.z, t.w, A, lane); apply_rz_t<7>(t.z, t.w, Bs, lane);
        apply_cnot_t<0>(A, lane); apply_cnot_t<0>(Bs, lane);
        apply_cnot_t<1>(A, lane); apply_cnot_t<1>(Bs, lane);
        apply_cnot_t<2>(A, lane); apply_cnot_t<2>(Bs, lane);
        apply_cnot_t<3>(A, lane); apply_cnot_t<3>(Bs, lane);
        apply_cnot_t<4>(A, lane); apply_cnot_t<4>(Bs, lane);
        apply_cnot_t<5>(A, lane); apply_cnot_t<5>(Bs, lane);
        apply_cnot_t<6>(A, lane); apply_cnot_t<6>(Bs, lane);
        apply_cnot_t<7>(A, lane); apply_cnot_t<7>(Bs, lane);
    }

    float z0[8], z1[8];
    measure_z(A, lane, z0);
    measure_z(Bs, lane, z1);

    if (lane == 0) {
        *(float4*)(zws + s0 * 8)     = make_float4(z0[0], z0[1], z0[2], z0[3]);
        *(float4*)(zws + s0 * 8 + 4) = make_float4(z0[4], z0[5], z0[6], z0[7]);
        *(float4*)(zws + s1 * 8)     = make_float4(z1[0], z1[1], z1[2], z1[3]);
        *(float4*)(zws + s1 * 8 + 4) = make_float4(z1[4], z1[5], z1[6], z1[7]);
    }
}

// ============ Kernel B: z -> out (register-blocked MLP, spill-safe) ============
// 256 threads, 16 samples/block. Phase 2: each thread = 4 cols x 4 samples,
// acc = 16 VGPR; W2 loop unrolled only 2x to bound in-flight loads.
__global__ __launch_bounds__(256) void qmlp2(
    const float* __restrict__ zws,      // [B,8]
    const float* __restrict__ W1,       // [8,64]
    const float* __restrict__ b1,       // [64]
    const float* __restrict__ W2,       // [64,256]
    const float* __restrict__ b2,       // [256]
    float* __restrict__ out,            // [B,256]
    int B)
{
    __shared__ float h_lds[16][64];

    int t = threadIdx.x;
    int sbase = blockIdx.x * 16;

    // phase 1: h[16][64] tile; thread t -> sample t>>4, cols (t&15)*4
    {
        int s_l = t >> 4;
        int i_l = (t & 15) * 4;
        int srow = sbase + s_l; if (srow >= B) srow = B - 1;
        const float* zr = zws + srow * 8;
        float4 za = *(const float4*)zr;
        float4 zb = *(const float4*)(zr + 4);
        float zq[8] = {za.x, za.y, za.z, za.w, zb.x, zb.y, zb.z, zb.w};
        float4 acc = *(const float4*)(b1 + i_l);
#pragma unroll
        for (int q = 0; q < 8; ++q) {
            float4 w = *(const float4*)(W1 + q * 64 + i_l);
            acc.x += zq[q] * w.x; acc.y += zq[q] * w.y;
            acc.z += zq[q] * w.z; acc.w += zq[q] * w.w;
        }
        acc.x = fmaxf(acc.x, 0.f); acc.y = fmaxf(acc.y, 0.f);
        acc.z = fmaxf(acc.z, 0.f); acc.w = fmaxf(acc.w, 0.f);
        *(float4*)&h_lds[s_l][i_l] = acc;
    }
    __syncthreads();

    // phase 2
    int sg = t >> 6;                    // 0..3 -> local samples sg*4 .. +3
    int c4 = (t & 63) * 4;
    float4 bb = *(const float4*)(b2 + c4);
    float4 a0 = bb, a1 = bb, a2 = bb, a3 = bb;
    const int sO = sg * 4;

#pragma unroll 2
    for (int i4 = 0; i4 < 16; ++i4) {
        const float* wrow = W2 + i4 * 4 * 256 + c4;
        float4 w0 = *(const float4*)(wrow);
        float4 w1 = *(const float4*)(wrow + 256);
        float4 w2 = *(const float4*)(wrow + 512);
        float4 w3 = *(const float4*)(wrow + 768);
        float4 h0 = *(const float4*)&h_lds[sO + 0][i4 * 4];
        float4 h1 = *(const float4*)&h_lds[sO + 1][i4 * 4];
        float4 h2 = *(const float4*)&h_lds[sO + 2][i4 * 4];
        float4 h3 = *(const float4*)&h_lds[sO + 3][i4 * 4];

        a0.x += h0.x*w0.x + h0.y*w1.x + h0.z*w2.x + h0.w*w3.x;
        a0.y += h0.x*w0.y + h0.y*w1.y + h0.z*w2.y + h0.w*w3.y;
        a0.z += h0.x*w0.z + h0.y*w1.z + h0.z*w2.z + h0.w*w3.z;
        a0.w += h0.x*w0.w + h0.y*w1.w + h0.z*w2.w + h0.w*w3.w;

        a1.x += h1.x*w0.x + h1.y*w1.x + h1.z*w2.x + h1.w*w3.x;
        a1.y += h1.x*w0.y + h1.y*w1.y + h1.z*w2.y + h1.w*w3.y;
        a1.z += h1.x*w0.z + h1.y*w1.z + h1.z*w2.z + h1.w*w3.z;
        a1.w += h1.x*w0.w + h1.y*w1.w + h1.z*w2.w + h1.w*w3.w;

        a2.x += h2.x*w0.x + h2.y*w1.x + h2.z*w2.x + h2.w*w3.x;
        a2.y += h2.x*w0.y + h2.y*w1.y + h2.z*w2.y + h2.w*w3.y;
        a2.z += h2.x*w0.z + h2.y*w1.z + h2.z*w2.z + h2.w*w3.z;
        a2.w += h2.x*w0.w + h2.y*w1.w + h2.z*w2.w + h2.w*w3.w;

        a3.x += h3.x*w0.x + h3.y*w1.x + h3.z*w2.x + h3.w*w3.x;
        a3.y += h3.x*w0.y + h3.y*w1.y + h3.z*w2.y + h3.w*w3.y;
        a3.z += h3.x*w0.z + h3.y*w1.z + h3.z*w2.z + h3.w*w3.z;
        a3.w += h3.x*w0.w + h3.y*w1.w + h3.z*w2.w + h3.w*w3.w;
    }

    int srow = sbase + sO;
    if (srow + 0 < B) *(float4*)(out + (srow + 0) * 256 + c4) = a0;
    if (srow + 1 < B) *(float4*)(out + (srow + 1) * 256 + c4) = a1;
    if (srow + 2 < B) *(float4*)(out + (srow + 2) * 256 + c4) = a2;
    if (srow + 3 < B) *(float4*)(out + (srow + 3) * 256 + c4) = a3;
}

extern "C" void kernel_launch(void* const* d_in, const int* in_sizes, int n_in,
                              void* d_out, int out_size, void* d_ws, size_t ws_size,
                              hipStream_t stream) {
    const float* x  = (const float*)d_in[0];
    const float* qw = (const float*)d_in[1];
    const float* W1 = (const float*)d_in[2];
    const float* b1 = (const float*)d_in[3];
    const float* W2 = (const float*)d_in[4];
    const float* b2 = (const float*)d_in[5];
    float* out = (float*)d_out;
    float* zws = (float*)d_ws;          // needs B*8*4 = 256 KiB

    int B = in_sizes[0] / NQ;           // 8192

    qcircuit_z<<<(B + 7) / 8, 256, 0, stream>>>(x, qw, zws, B);
    qmlp2<<<(B + 15) / 16, 256, 0, stream>>>(zws, W1, b1, W2, b2, out, B);
}

// Round 5
// 30.151 us; speedup vs baseline: 3.0785x; 1.2393x over previous
//
#include <hip/hip_runtime.h>

#define NQ 8
#define NLAYERS 3

typedef unsigned int uint2ev __attribute__((ext_vector_type(2)));

// ---- cross-lane xor exchange, off the DS pipe where possible ----
template<int MASK>
__device__ __forceinline__ float xorlane(float v, int lane) {
    if constexpr (MASK == 1) {
        return __int_as_float(__builtin_amdgcn_mov_dpp(__float_as_int(v), 0xB1, 0xF, 0xF, false)); // quad_perm [1,0,3,2]
    } else if constexpr (MASK == 2) {
        return __int_as_float(__builtin_amdgcn_mov_dpp(__float_as_int(v), 0x4E, 0xF, 0xF, false)); // quad_perm [2,3,0,1]
    } else if constexpr (MASK == 8) {
        return __int_as_float(__builtin_amdgcn_mov_dpp(__float_as_int(v), 0x128, 0xF, 0xF, false)); // row_ror:8 == xor 8
    }
#if __has_builtin(__builtin_amdgcn_permlane16_swap)
    else if constexpr (MASK == 16) {
        uint2ev r = __builtin_amdgcn_permlane16_swap(__float_as_uint(v), __float_as_uint(v), false, false);
        return __uint_as_float((lane & 16) ? r.x : r.y);
    }
#endif
#if __has_builtin(__builtin_amdgcn_permlane32_swap)
    else if constexpr (MASK == 32) {
        uint2ev r = __builtin_amdgcn_permlane32_swap(__float_as_uint(v), __float_as_uint(v), false, false);
        return __uint_as_float((lane & 32) ? r.x : r.y);
    }
#endif
    else {
        return __shfl_xor(v, MASK);
    }
}

// ---- DPP-fused wave64 sum; total lands in lane 63, zero DS ops ----
template<int CTRL>
__device__ __forceinline__ float dpp_add_stage(float v) {
    int moved = __builtin_amdgcn_update_dpp(0, __float_as_int(v), CTRL, 0xF, 0xF, false);
    return v + __int_as_float(moved);
}
__device__ __forceinline__ float wave_sum63(float v) {
    v = dpp_add_stage<0x111>(v);   // row_shr:1
    v = dpp_add_stage<0x112>(v);   // row_shr:2
    v = dpp_add_stage<0x114>(v);   // row_shr:4
    v = dpp_add_stage<0x118>(v);   // row_shr:8
    v = dpp_add_stage<0x142>(v);   // row_bcast:15
    v = dpp_add_stage<0x143>(v);   // row_bcast:31
    return v;                      // lane 63 has the full sum
}

__device__ __forceinline__ void ry_pair(float c, float s, float& a0, float& a1) {
    float n0 = c * a0 - s * a1;
    float n1 = s * a0 + c * a1;
    a0 = n0; a1 = n1;
}

template<int Q>
__device__ __forceinline__ void apply_ry_t(float c, float s, float ar[4], float ai[4], int lane) {
    if constexpr (Q == 0) {
        ry_pair(c, s, ar[0], ar[1]); ry_pair(c, s, ai[0], ai[1]);
        ry_pair(c, s, ar[2], ar[3]); ry_pair(c, s, ai[2], ai[3]);
    } else if constexpr (Q == 1) {
        ry_pair(c, s, ar[0], ar[2]); ry_pair(c, s, ai[0], ai[2]);
        ry_pair(c, s, ar[1], ar[3]); ry_pair(c, s, ai[1], ai[3]);
    } else {
        constexpr int mask = 1 << (Q - 2);
        float sgn = (lane & mask) ? s : -s;
#pragma unroll
        for (int j = 0; j < 4; ++j) {
            float pr = xorlane<mask>(ar[j], lane);
            float pq = xorlane<mask>(ai[j], lane);
            ar[j] = c * ar[j] + sgn * pr;
            ai[j] = c * ai[j] + sgn * pq;
        }
    }
}

__device__ __forceinline__ void rz_amp(float cp, float ssp, float& r, float& i) {
    float nr = r * cp - i * ssp;
    float ni = i * cp + r * ssp;
    r = nr; i = ni;
}

template<int Q>
__device__ __forceinline__ void apply_rz_t(float cp, float sp, float ar[4], float ai[4], int lane) {
    if constexpr (Q == 0) {
        rz_amp(cp, -sp, ar[0], ai[0]); rz_amp(cp,  sp, ar[1], ai[1]);
        rz_amp(cp, -sp, ar[2], ai[2]); rz_amp(cp,  sp, ar[3], ai[3]);
    } else if constexpr (Q == 1) {
        rz_amp(cp, -sp, ar[0], ai[0]); rz_amp(cp, -sp, ar[1], ai[1]);
        rz_amp(cp,  sp, ar[2], ai[2]); rz_amp(cp,  sp, ar[3], ai[3]);
    } else {
        float ssp = (lane & (1 << (Q - 2))) ? sp : -sp;
#pragma unroll
        for (int j = 0; j < 4; ++j) rz_amp(cp, ssp, ar[j], ai[j]);
    }
}

// CNOT(c, (c+1)%8)
template<int C>
__device__ __forceinline__ void apply_cnot_t(float ar[4], float ai[4], int lane) {
    if constexpr (C == 0) {
        float t;
        t = ar[1]; ar[1] = ar[3]; ar[3] = t;
        t = ai[1]; ai[1] = ai[3]; ai[3] = t;
    } else if constexpr (C == 1) {
        ar[2] = xorlane<1>(ar[2], lane); ai[2] = xorlane<1>(ai[2], lane);
        ar[3] = xorlane<1>(ar[3], lane); ai[3] = xorlane<1>(ai[3], lane);
    } else if constexpr (C == 7) {
        bool hi = (lane & 32) != 0;
        float t0 = ar[0]; ar[0] = hi ? ar[1] : ar[0]; ar[1] = hi ? t0 : ar[1];
        float u0 = ai[0]; ai[0] = hi ? ai[1] : ai[0]; ai[1] = hi ? u0 : ai[1];
        float t2 = ar[2]; ar[2] = hi ? ar[3] : ar[2]; ar[3] = hi ? t2 : ar[3];
        float u2 = ai[2]; ai[2] = hi ? ai[3] : ai[2]; ai[3] = hi ? u2 : ai[3];
    } else {
        constexpr int cm = 1 << (C - 2);
        constexpr int tm = 1 << (C - 1);
        bool hi = (lane & cm) != 0;
#pragma unroll
        for (int j = 0; j < 4; ++j) {
            float pr = xorlane<tm>(ar[j], lane);
            float pq = xorlane<tm>(ai[j], lane);
            ar[j] = hi ? pr : ar[j];
            ai[j] = hi ? pq : ai[j];
        }
    }
}

// ============ Kernel A: reduced circuit -> z[B][8] ============
// Algebraic reductions (all exact):
//  - layer0 RY folded into encoding angles (RY angles add on |0>)
//  - layer0 RZ folded into complex product-state construction (diagonal)
//  - layer2 RZ deleted (followed only by permutation + |amp|^2)
//  - layer2 CNOT ring deleted; measurement masks remapped through the ring
//    permutation: m_0 = 0xFE, m_q = 2^{q+1}-1 (q>=1)  [prefix parities]
__global__ __launch_bounds__(256) void qcircuit_z(
    const float* __restrict__ x,        // [B,8]
    const float* __restrict__ qw,       // [3,8,2]
    float* __restrict__ zws,            // [B,8]
    int B)
{
    // tab[q]     (layer0): {0.5*w_ry (raw), 0, cos(0.5*w_rz), sin(0.5*w_rz)}
    // tab[8+q]   (layer1): {cos, sin of 0.5*w_ry, cos, sin of 0.5*w_rz}
    // tab[16+q]  (layer2): same form (only .x,.y used)
    __shared__ float4 tab[NLAYERS * NQ];

    int tid = threadIdx.x;
    if (tid < NLAYERS * NQ) {
        float w0 = 0.5f * qw[tid * 2 + 0];
        float w1 = 0.5f * qw[tid * 2 + 1];
        if (tid < 8)
            tab[tid] = make_float4(w0, 0.f, __cosf(w1), __sinf(w1));
        else
            tab[tid] = make_float4(__cosf(w0), __sinf(w0), __cosf(w1), __sinf(w1));
    }
    __syncthreads();

    int lane = tid & 63;
    int wid  = tid >> 6;
    int sample = blockIdx.x * 4 + wid;
    if (sample >= B) return;

    // ---- load x row, normalize ----
    const float4* x4 = (const float4*)(x + sample * 8);
    float4 xa = x4[0], xb = x4[1];
    float xs[8] = {xa.x, xa.y, xa.z, xa.w, xb.x, xb.y, xb.z, xb.w};
    float xmin = xs[0], xmax = xs[0];
#pragma unroll
    for (int q = 1; q < 8; ++q) {
        xmin = fminf(xmin, xs[q]);
        xmax = fmaxf(xmax, xs[q]);
    }
    float inv_pi2 = 1.5707963267948966f / (xmax - xmin + 1e-8f);

    // ---- initial state: product of complex per-qubit factors ----
    // factor_q = RZ(w0q1)*RY(enc+w0q0)|0> = (c*cw - i*c*sw,  s*cw + i*s*sw)
    // lane-qubit (q>=2) chain:
    float plr, pli;
    {
        float4 t0 = tab[2];
        float a = fmaf(xs[2] - xmin, inv_pi2, t0.x);
        float c = __cosf(a), s = __sinf(a);
        int b = lane & 1;
        float f  = b ? s : c;
        float fr = f * t0.z;
        float fi = f * t0.w;
        plr = fr;
        pli = b ? fi : -fi;
    }
#pragma unroll
    for (int q = 3; q < 8; ++q) {
        float4 t0 = tab[q];
        float a = fmaf(xs[q] - xmin, inv_pi2, t0.x);
        float c = __cosf(a), s = __sinf(a);
        int b = (lane >> (q - 2)) & 1;
        float f  = b ? s : c;
        float fr = f * t0.z;
        float fi = f * t0.w;
        fi = b ? fi : -fi;
        float nr = plr * fr - pli * fi;
        float ni = plr * fi + pli * fr;
        plr = nr; pli = ni;
    }

    // local qubits 0,1 (j bits 0,1)
    float4 t00 = tab[0];
    float a0q = fmaf(xs[0] - xmin, inv_pi2, t00.x);
    float c0 = __cosf(a0q), s0 = __sinf(a0q);
    float v0r0 = c0 * t00.z, v0i0 = -c0 * t00.w;
    float v0r1 = s0 * t00.z, v0i1 =  s0 * t00.w;

    float4 t01 = tab[1];
    float a1q = fmaf(xs[1] - xmin, inv_pi2, t01.x);
    float c1 = __cosf(a1q), s1 = __sinf(a1q);
    float v1r0 = c1 * t01.z, v1i0 = -c1 * t01.w;
    float v1r1 = s1 * t01.z, v1i1 =  s1 * t01.w;

    float wr[4], wi[4];
    wr[0] = v0r0 * v1r0 - v0i0 * v1i0;  wi[0] = v0r0 * v1i0 + v0i0 * v1r0;
    wr[1] = v0r1 * v1r0 - v0i1 * v1i0;  wi[1] = v0r1 * v1i0 + v0i1 * v1r0;
    wr[2] = v0r0 * v1r1 - v0i0 * v1i1;  wi[2] = v0r0 * v1i1 + v0i0 * v1r1;
    wr[3] = v0r1 * v1r1 - v0i1 * v1i1;  wi[3] = v0r1 * v1i1 + v0i1 * v1r1;

    float ar[4], ai[4];
#pragma unroll
    for (int j = 0; j < 4; ++j) {
        ar[j] = plr * wr[j] - pli * wi[j];
        ai[j] = plr * wi[j] + pli * wr[j];
    }

    // ---- layer 0 CNOT ring ----
    apply_cnot_t<0>(ar, ai, lane);
    apply_cnot_t<1>(ar, ai, lane);
    apply_cnot_t<2>(ar, ai, lane);
    apply_cnot_t<3>(ar, ai, lane);
    apply_cnot_t<4>(ar, ai, lane);
    apply_cnot_t<5>(ar, ai, lane);
    apply_cnot_t<6>(ar, ai, lane);
    apply_cnot_t<7>(ar, ai, lane);

    // ---- layer 1: RY + RZ all qubits, then CNOT ring ----
    {
        float4 t;
        t = tab[8];  apply_ry_t<0>(t.x, t.y, ar, ai, lane); apply_rz_t<0>(t.z, t.w, ar, ai, lane);
        t = tab[9];  apply_ry_t<1>(t.x, t.y, ar, ai, lane); apply_rz_t<1>(t.z, t.w, ar, ai, lane);
        t = tab[10]; apply_ry_t<2>(t.x, t.y, ar, ai, lane); apply_rz_t<2>(t.z, t.w, ar, ai, lane);
        t = tab[11]; apply_ry_t<3>(t.x, t.y, ar, ai, lane); apply_rz_t<3>(t.z, t.w, ar, ai, lane);
        t = tab[12]; apply_ry_t<4>(t.x, t.y, ar, ai, lane); apply_rz_t<4>(t.z, t.w, ar, ai, lane);
        t = tab[13]; apply_ry_t<5>(t.x, t.y, ar, ai, lane); apply_rz_t<5>(t.z, t.w, ar, ai, lane);
        t = tab[14]; apply_ry_t<6>(t.x, t.y, ar, ai, lane); apply_rz_t<6>(t.z, t.w, ar, ai, lane);
        t = tab[15]; apply_ry_t<7>(t.x, t.y, ar, ai, lane); apply_rz_t<7>(t.z, t.w, ar, ai, lane);
    }
    apply_cnot_t<0>(ar, ai, lane);
    apply_cnot_t<1>(ar, ai, lane);
    apply_cnot_t<2>(ar, ai, lane);
    apply_cnot_t<3>(ar, ai, lane);
    apply_cnot_t<4>(ar, ai, lane);
    apply_cnot_t<5>(ar, ai, lane);
    apply_cnot_t<6>(ar, ai, lane);
    apply_cnot_t<7>(ar, ai, lane);

    // ---- layer 2: RY only (RZ + ring folded into measurement) ----
    {
        float4 t;
        t = tab[16]; apply_ry_t<0>(t.x, t.y, ar, ai, lane);
        t = tab[17]; apply_ry_t<1>(t.x, t.y, ar, ai, lane);
        t = tab[18]; apply_ry_t<2>(t.x, t.y, ar, ai, lane);
        t = tab[19]; apply_ry_t<3>(t.x, t.y, ar, ai, lane);
        t = tab[20]; apply_ry_t<4>(t.x, t.y, ar, ai, lane);
        t = tab[21]; apply_ry_t<5>(t.x, t.y, ar, ai, lane);
        t = tab[22]; apply_ry_t<6>(t.x, t.y, ar, ai, lane);
        t = tab[23]; apply_ry_t<7>(t.x, t.y, ar, ai, lane);
    }

    // ---- measurement through the (deleted) final ring ----
    // z_q = sum_i (-1)^{parity(m_q & i)} |amp_i|^2,  i = (lane<<2)|j
    // m_0 = 0xFE (j-bit1, lane mask 0x3F); m_q = 2^{q+1}-1 (q>=1):
    //   j-part = 0x3; lane masks: 0,1,3,7,0xF,0x1F,0x3F  (prefix parities)
    float p0 = ar[0] * ar[0] + ai[0] * ai[0];
    float p1 = ar[1] * ar[1] + ai[1] * ai[1];
    float p2 = ar[2] * ar[2] + ai[2] * ai[2];
    float p3 = ar[3] * ar[3] + ai[3] * ai[3];

    float T33 = (p0 - p1) - (p2 - p3);   // signs (+,-,-,+) : parity(3&j)
    float T2  = (p0 + p1) - (p2 + p3);   // signs (+,+,-,-) : parity(2&j)

    int pp1 = lane & 1;
    int pp2 = pp1 ^ ((lane >> 1) & 1);
    int pp3 = pp2 ^ ((lane >> 2) & 1);
    int pp4 = pp3 ^ ((lane >> 3) & 1);
    int pp5 = pp4 ^ ((lane >> 4) & 1);
    int pp6 = pp5 ^ ((lane >> 5) & 1);

    float z0 = wave_sum63(pp6 ? -T2  : T2);
    float z1 = wave_sum63(T33);
    float z2 = wave_sum63(pp1 ? -T33 : T33);
    float z3 = wave_sum63(pp2 ? -T33 : T33);
    float z4 = wave_sum63(pp3 ? -T33 : T33);
    float z5 = wave_sum63(pp4 ? -T33 : T33);
    float z6 = wave_sum63(pp5 ? -T33 : T33);
    float z7 = wave_sum63(pp6 ? -T33 : T33);

    if (lane == 63) {
        *(float4*)(zws + sample * 8)     = make_float4(z0, z1, z2, z3);
        *(float4*)(zws + sample * 8 + 4) = make_float4(z4, z5, z6, z7);
    }
}

// ============ Kernel B: z -> out (register-blocked MLP, spill-safe) ============
__global__ __launch_bounds__(256) void qmlp2(
    const float* __restrict__ zws,      // [B,8]
    const float* __restrict__ W1,       // [8,64]
    const float* __restrict__ b1,       // [64]
    const float* __restrict__ W2,       // [64,256]
    const float* __restrict__ b2,       // [256]
    float* __restrict__ out,            // [B,256]
    int B)
{
    __shared__ float h_lds[16][64];

    int t = threadIdx.x;
    int sbase = blockIdx.x * 16;

    // phase 1: h[16][64] tile
    {
        int s_l = t >> 4;
        int i_l = (t & 15) * 4;
        int srow = sbase + s_l; if (srow >= B) srow = B - 1;
        const float* zr = zws + srow * 8;
        float4 za = *(const float4*)zr;
        float4 zb = *(const float4*)(zr + 4);
        float zq[8] = {za.x, za.y, za.z, za.w, zb.x, zb.y, zb.z, zb.w};
        float4 acc = *(const float4*)(b1 + i_l);
#pragma unroll
        for (int q = 0; q < 8; ++q) {
            float4 w = *(const float4*)(W1 + q * 64 + i_l);
            acc.x += zq[q] * w.x; acc.y += zq[q] * w.y;
            acc.z += zq[q] * w.z; acc.w += zq[q] * w.w;
        }
        acc.x = fmaxf(acc.x, 0.f); acc.y = fmaxf(acc.y, 0.f);
        acc.z = fmaxf(acc.z, 0.f); acc.w = fmaxf(acc.w, 0.f);
        *(float4*)&h_lds[s_l][i_l] = acc;
    }
    __syncthreads();

    // phase 2: out = h @ W2 + b2 ; 4 samples x 4 cols per thread
    int sg = t >> 6;
    int c4 = (t & 63) * 4;
    float4 bb = *(const float4*)(b2 + c4);
    float4 a0 = bb, a1 = bb, a2 = bb, a3 = bb;
    const int sO = sg * 4;

#pragma unroll 2
    for (int i4 = 0; i4 < 16; ++i4) {
        const float* wrow = W2 + i4 * 4 * 256 + c4;
        float4 w0 = *(const float4*)(wrow);
        float4 w1 = *(const float4*)(wrow + 256);
        float4 w2 = *(const float4*)(wrow + 512);
        float4 w3 = *(const float4*)(wrow + 768);
        float4 h0 = *(const float4*)&h_lds[sO + 0][i4 * 4];
        float4 h1 = *(const float4*)&h_lds[sO + 1][i4 * 4];
        float4 h2 = *(const float4*)&h_lds[sO + 2][i4 * 4];
        float4 h3 = *(const float4*)&h_lds[sO + 3][i4 * 4];

        a0.x += h0.x*w0.x + h0.y*w1.x + h0.z*w2.x + h0.w*w3.x;
        a0.y += h0.x*w0.y + h0.y*w1.y + h0.z*w2.y + h0.w*w3.y;
        a0.z += h0.x*w0.z + h0.y*w1.z + h0.z*w2.z + h0.w*w3.z;
        a0.w += h0.x*w0.w + h0.y*w1.w + h0.z*w2.w + h0.w*w3.w;

        a1.x += h1.x*w0.x + h1.y*w1.x + h1.z*w2.x + h1.w*w3.x;
        a1.y += h1.x*w0.y + h1.y*w1.y + h1.z*w2.y + h1.w*w3.y;
        a1.z += h1.x*w0.z + h1.y*w1.z + h1.z*w2.z + h1.w*w3.z;
        a1.w += h1.x*w0.w + h1.y*w1.w + h1.z*w2.w + h1.w*w3.w;

        a2.x += h2.x*w0.x + h2.y*w1.x + h2.z*w2.x + h2.w*w3.x;
        a2.y += h2.x*w0.y + h2.y*w1.y + h2.z*w2.y + h2.w*w3.y;
        a2.z += h2.x*w0.z + h2.y*w1.z + h2.z*w2.z + h2.w*w3.z;
        a2.w += h2.x*w0.w + h2.y*w1.w + h2.z*w2.w + h2.w*w3.w;

        a3.x += h3.x*w0.x + h3.y*w1.x + h3.z*w2.x + h3.w*w3.x;
        a3.y += h3.x*w0.y + h3.y*w1.y + h3.z*w2.y + h3.w*w3.y;
        a3.z += h3.x*w0.z + h3.y*w1.z + h3.z*w2.z + h3.w*w3.z;
        a3.w += h3.x*w0.w + h3.y*w1.w + h3.z*w2.w + h3.w*w3.w;
    }

    int srow = sbase + sO;
    if (srow + 0 < B) *(float4*)(out + (srow + 0) * 256 + c4) = a0;
    if (srow + 1 < B) *(float4*)(out + (srow + 1) * 256 + c4) = a1;
    if (srow + 2 < B) *(float4*)(out + (srow + 2) * 256 + c4) = a2;
    if (srow + 3 < B) *(float4*)(out + (srow + 3) * 256 + c4) = a3;
}

extern "C" void kernel_launch(void* const* d_in, const int* in_sizes, int n_in,
                              void* d_out, int out_size, void* d_ws, size_t ws_size,
                              hipStream_t stream) {
    const float* x  = (const float*)d_in[0];
    const float* qw = (const float*)d_in[1];
    const float* W1 = (const float*)d_in[2];
    const float* b1 = (const float*)d_in[3];
    const float* W2 = (const float*)d_in[4];
    const float* b2 = (const float*)d_in[5];
    float* out = (float*)d_out;
    float* zws = (float*)d_ws;          // needs B*8*4 = 256 KiB

    int B = in_sizes[0] / NQ;           // 8192

    qcircuit_z<<<(B + 3) / 4, 256, 0, stream>>>(x, qw, zws, B);
    qmlp2<<<(B + 15) / 16, 256, 0, stream>>>(zws, W1, b1, W2, b2, out, B);
}

// Round 7
// 30.041 us; speedup vs baseline: 3.0897x; 1.0036x over previous
//
#include <hip/hip_runtime.h>

#define NQ 8
#define NLAYERS 3

typedef unsigned int uint2ev __attribute__((ext_vector_type(2)));

// ---- cross-lane xor exchange, zero DS ops for all masks ----
// 1,2 -> quad_perm; 4 -> row_shr:4/row_shl:4 + select; 8 -> row_ror:8;
// 16/32 -> permlane*_swap.
template<int MASK>
__device__ __forceinline__ float xorlane(float v, int lane) {
    if constexpr (MASK == 1) {
        return __int_as_float(__builtin_amdgcn_mov_dpp(__float_as_int(v), 0xB1, 0xF, 0xF, false)); // quad_perm [1,0,3,2]
    } else if constexpr (MASK == 2) {
        return __int_as_float(__builtin_amdgcn_mov_dpp(__float_as_int(v), 0x4E, 0xF, 0xF, false)); // quad_perm [2,3,0,1]
    } else if constexpr (MASK == 4) {
        // xor4 within 16-lane row: lanes bit2=1 take row_shr:4, bit2=0 take row_shl:4
        float a = __int_as_float(__builtin_amdgcn_update_dpp(0, __float_as_int(v), 0x114, 0xF, 0xF, false)); // row_shr:4
        float b = __int_as_float(__builtin_amdgcn_update_dpp(0, __float_as_int(v), 0x104, 0xF, 0xF, false)); // row_shl:4
        return (lane & 4) ? a : b;
    } else if constexpr (MASK == 8) {
        return __int_as_float(__builtin_amdgcn_mov_dpp(__float_as_int(v), 0x128, 0xF, 0xF, false)); // row_ror:8 == xor 8
    }
#if __has_builtin(__builtin_amdgcn_permlane16_swap)
    else if constexpr (MASK == 16) {
        uint2ev r = __builtin_amdgcn_permlane16_swap(__float_as_uint(v), __float_as_uint(v), false, false);
        return __uint_as_float((lane & 16) ? r.x : r.y);
    }
#endif
#if __has_builtin(__builtin_amdgcn_permlane32_swap)
    else if constexpr (MASK == 32) {
        uint2ev r = __builtin_amdgcn_permlane32_swap(__float_as_uint(v), __float_as_uint(v), false, false);
        return __uint_as_float((lane & 32) ? r.x : r.y);
    }
#endif
    else {
        return __shfl_xor(v, MASK);
    }
}

// ---- DPP-fused wave64 sum; total lands in lane 63, zero DS ops ----
template<int CTRL>
__device__ __forceinline__ float dpp_add_stage(float v) {
    int moved = __builtin_amdgcn_update_dpp(0, __float_as_int(v), CTRL, 0xF, 0xF, false);
    return v + __int_as_float(moved);
}
__device__ __forceinline__ float wave_sum63(float v) {
    v = dpp_add_stage<0x111>(v);   // row_shr:1
    v = dpp_add_stage<0x112>(v);   // row_shr:2
    v = dpp_add_stage<0x114>(v);   // row_shr:4
    v = dpp_add_stage<0x118>(v);   // row_shr:8
    v = dpp_add_stage<0x142>(v);   // row_bcast:15
    v = dpp_add_stage<0x143>(v);   // row_bcast:31
    return v;                      // lane 63 has the full sum
}

__device__ __forceinline__ void ry_pair(float c, float s, float& a0, float& a1) {
    float n0 = c * a0 - s * a1;
    float n1 = s * a0 + c * a1;
    a0 = n0; a1 = n1;
}

template<int Q>
__device__ __forceinline__ void apply_ry_t(float c, float s, float ar[4], float ai[4], int lane) {
    if constexpr (Q == 0) {
        ry_pair(c, s, ar[0], ar[1]); ry_pair(c, s, ai[0], ai[1]);
        ry_pair(c, s, ar[2], ar[3]); ry_pair(c, s, ai[2], ai[3]);
    } else if constexpr (Q == 1) {
        ry_pair(c, s, ar[0], ar[2]); ry_pair(c, s, ai[0], ai[2]);
        ry_pair(c, s, ar[1], ar[3]); ry_pair(c, s, ai[1], ai[3]);
    } else {
        constexpr int mask = 1 << (Q - 2);
        float sgn = (lane & mask) ? s : -s;
#pragma unroll
        for (int j = 0; j < 4; ++j) {
            float pr = xorlane<mask>(ar[j], lane);
            float pq = xorlane<mask>(ai[j], lane);
            ar[j] = c * ar[j] + sgn * pr;
            ai[j] = c * ai[j] + sgn * pq;
        }
    }
}

__device__ __forceinline__ void rz_amp(float cp, float ssp, float& r, float& i) {
    float nr = r * cp - i * ssp;
    float ni = i * cp + r * ssp;
    r = nr; i = ni;
}

template<int Q>
__device__ __forceinline__ void apply_rz_t(float cp, float sp, float ar[4], float ai[4], int lane) {
    if constexpr (Q == 0) {
        rz_amp(cp, -sp, ar[0], ai[0]); rz_amp(cp,  sp, ar[1], ai[1]);
        rz_amp(cp, -sp, ar[2], ai[2]); rz_amp(cp,  sp, ar[3], ai[3]);
    } else if constexpr (Q == 1) {
        rz_amp(cp, -sp, ar[0], ai[0]); rz_amp(cp, -sp, ar[1], ai[1]);
        rz_amp(cp,  sp, ar[2], ai[2]); rz_amp(cp,  sp, ar[3], ai[3]);
    } else {
        float ssp = (lane & (1 << (Q - 2))) ? sp : -sp;
#pragma unroll
        for (int j = 0; j < 4; ++j) rz_amp(cp, ssp, ar[j], ai[j]);
    }
}

// CNOT(c, (c+1)%8)
template<int C>
__device__ __forceinline__ void apply_cnot_t(float ar[4], float ai[4], int lane) {
    if constexpr (C == 0) {
        float t;
        t = ar[1]; ar[1] = ar[3]; ar[3] = t;
        t = ai[1]; ai[1] = ai[3]; ai[3] = t;
    } else if constexpr (C == 1) {
        ar[2] = xorlane<1>(ar[2], lane); ai[2] = xorlane<1>(ai[2], lane);
        ar[3] = xorlane<1>(ar[3], lane); ai[3] = xorlane<1>(ai[3], lane);
    } else if constexpr (C == 7) {
        bool hi = (lane & 32) != 0;
        float t0 = ar[0]; ar[0] = hi ? ar[1] : ar[0]; ar[1] = hi ? t0 : ar[1];
        float u0 = ai[0]; ai[0] = hi ? ai[1] : ai[0]; ai[1] = hi ? u0 : ai[1];
        float t2 = ar[2]; ar[2] = hi ? ar[3] : ar[2]; ar[3] = hi ? t2 : ar[3];
        float u2 = ai[2]; ai[2] = hi ? ai[3] : ai[2]; ai[3] = hi ? u2 : ai[3];
    } else {
        constexpr int cm = 1 << (C - 2);
        constexpr int tm = 1 << (C - 1);
        bool hi = (lane & cm) != 0;
#pragma unroll
        for (int j = 0; j < 4; ++j) {
            float pr = xorlane<tm>(ar[j], lane);
            float pq = xorlane<tm>(ai[j], lane);
            ar[j] = hi ? pr : ar[j];
            ai[j] = hi ? pq : ai[j];
        }
    }
}

#define CMUL(rr, ri, xr, xi, yr, yi) { float _tr = (xr)*(yr) - (xi)*(yi); \
                                       float _ti = (xr)*(yi) + (xi)*(yr); \
                                       rr = _tr; ri = _ti; }

// ============ Kernel A: reduced circuit -> z[B][8] ============
// Exact reductions: layer0 RY folded into encoding; layer0 RZ folded into
// complex product factors; RING0 DELETED via inverse-permutation selectors
//   a0=i0^i7, a1=i0^i1^i7, a_k=i_{k-1}^i_k (k>=2)
// with i0,i1 = j bits, i_q = lane bit (q-2) for q>=2. So for qubit q>=3:
//   selector = l_{q-3} ^ l_{q-2}   <-- (round-6 bug was an off-by-one here)
// layer2 RZ deleted; layer2 ring folded into measurement prefix masks.
__global__ __launch_bounds__(512) void qcircuit_z(
    const float* __restrict__ x,        // [B,8]
    const float* __restrict__ qw,       // [3,8,2]
    float* __restrict__ zws,            // [B,8]
    int B)
{
    // tab[q]    (layer0): {0.5*w_ry (raw), 0, cos(0.5*w_rz), sin(0.5*w_rz)}
    // tab[8+q]  (layer1): {cos,sin of 0.5*w_ry, cos,sin of 0.5*w_rz}
    // tab[16+q] (layer2): {cos,sin of 0.5*w_ry, -, -}
    __shared__ float4 tab[NLAYERS * NQ];

    int tid = threadIdx.x;
    if (tid < NLAYERS * NQ) {
        float w0 = 0.5f * qw[tid * 2 + 0];
        float w1 = 0.5f * qw[tid * 2 + 1];
        if (tid < 8)
            tab[tid] = make_float4(w0, 0.f, __cosf(w1), __sinf(w1));
        else
            tab[tid] = make_float4(__cosf(w0), __sinf(w0), __cosf(w1), __sinf(w1));
    }
    __syncthreads();

    int lane = tid & 63;
    int wid  = tid >> 6;
    int sample = blockIdx.x * 8 + wid;
    if (sample >= B) return;

    // ---- load x row, normalize ----
    const float4* x4 = (const float4*)(x + sample * 8);
    float4 xa = x4[0], xb = x4[1];
    float xs[8] = {xa.x, xa.y, xa.z, xa.w, xb.x, xb.y, xb.z, xb.w};
    float xmin = xs[0], xmax = xs[0];
#pragma unroll
    for (int q = 1; q < 8; ++q) {
        xmin = fminf(xmin, xs[q]);
        xmax = fmaxf(xmax, xs[q]);
    }
    float inv_pi2 = 1.5707963267948966f / (xmax - xmin + 1e-8f);

    // per-qubit trig (encoding + layer0 RY fold)
    float cc[8], ss[8], cw[8], sw[8];
#pragma unroll
    for (int q = 0; q < 8; ++q) {
        float4 t0 = tab[q];
        float a = fmaf(xs[q] - xmin, inv_pi2, t0.x);
        cc[q] = __cosf(a);
        ss[q] = __sinf(a);
        cw[q] = t0.z;
        sw[q] = t0.w;
    }

    // ---- state construction with ring0 folded in (selector bits) ----
    // f_q(b) = ( r*cw_q , (b? +1 : -1) * r*sw_q ),  r = b? ss_q : cc_q
    // lane-only selectors (q>=3): sel_q = l_{q-3} ^ l_{q-2}
    float plr, pli;
    {
        int b = ((lane >> 0) ^ (lane >> 1)) & 1;     // q=3: l0^l1
        float r = b ? ss[3] : cc[3];
        plr = r * cw[3];
        pli = b ? r * sw[3] : -r * sw[3];
    }
#pragma unroll
    for (int q = 4; q < 8; ++q) {
        int b = ((lane >> (q - 3)) ^ (lane >> (q - 2))) & 1;   // FIXED off-by-one
        float r = b ? ss[q] : cc[q];
        float fr = r * cw[q];
        float fi = b ? r * sw[q] : -r * sw[q];
        CMUL(plr, pli, plr, pli, fr, fi);
    }

    // locals: u = lane bit5 (i7), v = lane bit0 (i2)
    int u = (lane >> 5) & 1;
    int v = lane & 1;

    // qubit0 selector = j0^u ; qubit1 selector = j0^j1^u ; qubit2 selector = j1^v
    // qubit0 factors: A (b=u, for j0=0), B (b=1^u, for j0=1)
    float r0A = u ? ss[0] : cc[0];
    float f0Ar = r0A * cw[0], f0Ai = (u ? r0A : -r0A) * sw[0];
    float r0B = u ? cc[0] : ss[0];
    float f0Br = r0B * cw[0], f0Bi = (u ? -r0B : r0B) * sw[0];
    // qubit1 factors: A (b=u), B (b=1^u)
    float r1A = u ? ss[1] : cc[1];
    float f1Ar = r1A * cw[1], f1Ai = (u ? r1A : -r1A) * sw[1];
    float r1B = u ? cc[1] : ss[1];
    float f1Br = r1B * cw[1], f1Bi = (u ? -r1B : r1B) * sw[1];
    // qubit2 factors: A (b=v), B (b=1^v)
    float r2A = v ? ss[2] : cc[2];
    float f2Ar = r2A * cw[2], f2Ai = (v ? r2A : -r2A) * sw[2];
    float r2B = v ? cc[2] : ss[2];
    float f2Br = r2B * cw[2], f2Bi = (v ? -r2B : r2B) * sw[2];

    // j=0: q0 sel=u (A), q1 sel=u (A), q2 sel=v (A)
    // j=1: q0 sel=1^u (B), q1 sel=1^u (B), q2 sel=v (A)
    // j=2: q0 sel=u (A), q1 sel=1^u (B), q2 sel=1^v (B)
    // j=3: q0 sel=1^u (B), q1 sel=u (A), q2 sel=1^v (B)
    float tAAr, tAAi, tBBr, tBBi, tABr, tABi, tBAr, tBAi;
    CMUL(tAAr, tAAi, f0Ar, f0Ai, f1Ar, f1Ai);
    CMUL(tBBr, tBBi, f0Br, f0Bi, f1Br, f1Bi);
    CMUL(tABr, tABi, f0Ar, f0Ai, f1Br, f1Bi);
    CMUL(tBAr, tBAi, f0Br, f0Bi, f1Ar, f1Ai);

    float ar[4], ai[4];
    CMUL(ar[0], ai[0], tAAr, tAAi, f2Ar, f2Ai);
    CMUL(ar[1], ai[1], tBBr, tBBi, f2Ar, f2Ai);
    CMUL(ar[2], ai[2], tABr, tABi, f2Br, f2Bi);
    CMUL(ar[3], ai[3], tBAr, tBAi, f2Br, f2Bi);
#pragma unroll
    for (int j = 0; j < 4; ++j) {
        CMUL(ar[j], ai[j], ar[j], ai[j], plr, pli);
    }
    // state now == ring0 applied to encoded+layer0-rotated product state

    // ---- layer 1: RY + RZ all qubits, then CNOT ring ----
    {
        float4 t;
        t = tab[8];  apply_ry_t<0>(t.x, t.y, ar, ai, lane); apply_rz_t<0>(t.z, t.w, ar, ai, lane);
        t = tab[9];  apply_ry_t<1>(t.x, t.y, ar, ai, lane); apply_rz_t<1>(t.z, t.w, ar, ai, lane);
        t = tab[10]; apply_ry_t<2>(t.x, t.y, ar, ai, lane); apply_rz_t<2>(t.z, t.w, ar, ai, lane);
        t = tab[11]; apply_ry_t<3>(t.x, t.y, ar, ai, lane); apply_rz_t<3>(t.z, t.w, ar, ai, lane);
        t = tab[12]; apply_ry_t<4>(t.x, t.y, ar, ai, lane); apply_rz_t<4>(t.z, t.w, ar, ai, lane);
        t = tab[13]; apply_ry_t<5>(t.x, t.y, ar, ai, lane); apply_rz_t<5>(t.z, t.w, ar, ai, lane);
        t = tab[14]; apply_ry_t<6>(t.x, t.y, ar, ai, lane); apply_rz_t<6>(t.z, t.w, ar, ai, lane);
        t = tab[15]; apply_ry_t<7>(t.x, t.y, ar, ai, lane); apply_rz_t<7>(t.z, t.w, ar, ai, lane);
    }
    apply_cnot_t<0>(ar, ai, lane);
    apply_cnot_t<1>(ar, ai, lane);
    apply_cnot_t<2>(ar, ai, lane);
    apply_cnot_t<3>(ar, ai, lane);
    apply_cnot_t<4>(ar, ai, lane);
    apply_cnot_t<5>(ar, ai, lane);
    apply_cnot_t<6>(ar, ai, lane);
    apply_cnot_t<7>(ar, ai, lane);

    // ---- layer 2: RY only (RZ + ring folded into measurement) ----
    {
        float4 t;
        t = tab[16]; apply_ry_t<0>(t.x, t.y, ar, ai, lane);
        t = tab[17]; apply_ry_t<1>(t.x, t.y, ar, ai, lane);
        t = tab[18]; apply_ry_t<2>(t.x, t.y, ar, ai, lane);
        t = tab[19]; apply_ry_t<3>(t.x, t.y, ar, ai, lane);
        t = tab[20]; apply_ry_t<4>(t.x, t.y, ar, ai, lane);
        t = tab[21]; apply_ry_t<5>(t.x, t.y, ar, ai, lane);
        t = tab[22]; apply_ry_t<6>(t.x, t.y, ar, ai, lane);
        t = tab[23]; apply_ry_t<7>(t.x, t.y, ar, ai, lane);
    }

    // ---- measurement through the (deleted) final ring ----
    float p0 = ar[0] * ar[0] + ai[0] * ai[0];
    float p1 = ar[1] * ar[1] + ai[1] * ai[1];
    float p2 = ar[2] * ar[2] + ai[2] * ai[2];
    float p3 = ar[3] * ar[3] + ai[3] * ai[3];

    float T33 = (p0 - p1) - (p2 - p3);   // parity(3&j)
    float T2  = (p0 + p1) - (p2 + p3);   // parity(2&j)

    int pp1 = lane & 1;
    int pp2 = pp1 ^ ((lane >> 1) & 1);
    int pp3 = pp2 ^ ((lane >> 2) & 1);
    int pp4 = pp3 ^ ((lane >> 3) & 1);
    int pp5 = pp4 ^ ((lane >> 4) & 1);
    int pp6 = pp5 ^ ((lane >> 5) & 1);

    float z0 = wave_sum63(pp6 ? -T2  : T2);
    float z1 = wave_sum63(T33);
    float z2 = wave_sum63(pp1 ? -T33 : T33);
    float z3 = wave_sum63(pp2 ? -T33 : T33);
    float z4 = wave_sum63(pp3 ? -T33 : T33);
    float z5 = wave_sum63(pp4 ? -T33 : T33);
    float z6 = wave_sum63(pp5 ? -T33 : T33);
    float z7 = wave_sum63(pp6 ? -T33 : T33);

    if (lane == 63) {
        *(float4*)(zws + sample * 8)     = make_float4(z0, z1, z2, z3);
        *(float4*)(zws + sample * 8 + 4) = make_float4(z4, z5, z6, z7);
    }
}

// ============ Kernel B: z -> out (register-blocked MLP, spill-safe) ============
__global__ __launch_bounds__(256) void qmlp2(
    const float* __restrict__ zws,      // [B,8]
    const float* __restrict__ W1,       // [8,64]
    const float* __restrict__ b1,       // [64]
    const float* __restrict__ W2,       // [64,256]
    const float* __restrict__ b2,       // [256]
    float* __restrict__ out,            // [B,256]
    int B)
{
    __shared__ float h_lds[16][64];

    int t = threadIdx.x;
    int sbase = blockIdx.x * 16;

    // phase 1: h[16][64] tile
    {
        int s_l = t >> 4;
        int i_l = (t & 15) * 4;
        int srow = sbase + s_l; if (srow >= B) srow = B - 1;
        const float* zr = zws + srow * 8;
        float4 za = *(const float4*)zr;
        float4 zb = *(const float4*)(zr + 4);
        float zq[8] = {za.x, za.y, za.z, za.w, zb.x, zb.y, zb.z, zb.w};
        float4 acc = *(const float4*)(b1 + i_l);
#pragma unroll
        for (int q = 0; q < 8; ++q) {
            float4 w = *(const float4*)(W1 + q * 64 + i_l);
            acc.x += zq[q] * w.x; acc.y += zq[q] * w.y;
            acc.z += zq[q] * w.z; acc.w += zq[q] * w.w;
        }
        acc.x = fmaxf(acc.x, 0.f); acc.y = fmaxf(acc.y, 0.f);
        acc.z = fmaxf(acc.z, 0.f); acc.w = fmaxf(acc.w, 0.f);
        *(float4*)&h_lds[s_l][i_l] = acc;
    }
    __syncthreads();

    // phase 2: out = h @ W2 + b2 ; 4 samples x 4 cols per thread
    int sg = t >> 6;
    int c4 = (t & 63) * 4;
    float4 bb = *(const float4*)(b2 + c4);
    float4 a0 = bb, a1 = bb, a2 = bb, a3 = bb;
    const int sO = sg * 4;

#pragma unroll 2
    for (int i4 = 0; i4 < 16; ++i4) {
        const float* wrow = W2 + i4 * 4 * 256 + c4;
        float4 w0 = *(const float4*)(wrow);
        float4 w1 = *(const float4*)(wrow + 256);
        float4 w2 = *(const float4*)(wrow + 512);
        float4 w3 = *(const float4*)(wrow + 768);
        float4 h0 = *(const float4*)&h_lds[sO + 0][i4 * 4];
        float4 h1 = *(const float4*)&h_lds[sO + 1][i4 * 4];
        float4 h2 = *(const float4*)&h_lds[sO + 2][i4 * 4];
        float4 h3 = *(const float4*)&h_lds[sO + 3][i4 * 4];

        a0.x += h0.x*w0.x + h0.y*w1.x + h0.z*w2.x + h0.w*w3.x;
        a0.y += h0.x*w0.y + h0.y*w1.y + h0.z*w2.y + h0.w*w3.y;
        a0.z += h0.x*w0.z + h0.y*w1.z + h0.z*w2.z + h0.w*w3.z;
        a0.w += h0.x*w0.w + h0.y*w1.w + h0.z*w2.w + h0.w*w3.w;

        a1.x += h1.x*w0.x + h1.y*w1.x + h1.z*w2.x + h1.w*w3.x;
        a1.y += h1.x*w0.y + h1.y*w1.y + h1.z*w2.y + h1.w*w3.y;
        a1.z += h1.x*w0.z + h1.y*w1.z + h1.z*w2.z + h1.w*w3.z;
        a1.w += h1.x*w0.w + h1.y*w1.w + h1.z*w2.w + h1.w*w3.w;

        a2.x += h2.x*w0.x + h2.y*w1.x + h2.z*w2.x + h2.w*w3.x;
        a2.y += h2.x*w0.y + h2.y*w1.y + h2.z*w2.y + h2.w*w3.y;
        a2.z += h2.x*w0.z + h2.y*w1.z + h2.z*w2.z + h2.w*w3.z;
        a2.w += h2.x*w0.w + h2.y*w1.w + h2.z*w2.w + h2.w*w3.w;

        a3.x += h3.x*w0.x + h3.y*w1.x + h3.z*w2.x + h3.w*w3.x;
        a3.y += h3.x*w0.y + h3.y*w1.y + h3.z*w2.y + h3.w*w3.y;
        a3.z += h3.x*w0.z + h3.y*w1.z + h3.z*w2.z + h3.w*w3.z;
        a3.w += h3.x*w0.w + h3.y*w1.w + h3.z*w2.w + h3.w*w3.w;
    }

    int srow = sbase + sO;
    if (srow + 0 < B) *(float4*)(out + (srow + 0) * 256 + c4) = a0;
    if (srow + 1 < B) *(float4*)(out + (srow + 1) * 256 + c4) = a1;
    if (srow + 2 < B) *(float4*)(out + (srow + 2) * 256 + c4) = a2;
    if (srow + 3 < B) *(float4*)(out + (srow + 3) * 256 + c4) = a3;
}

extern "C" void kernel_launch(void* const* d_in, const int* in_sizes, int n_in,
                              void* d_out, int out_size, void* d_ws, size_t ws_size,
                              hipStream_t stream) {
    const float* x  = (const float*)d_in[0];
    const float* qw = (const float*)d_in[1];
    const float* W1 = (const float*)d_in[2];
    const float* b1 = (const float*)d_in[3];
    const float* W2 = (const float*)d_in[4];
    const float* b2 = (const float*)d_in[5];
    float* out = (float*)d_out;
    float* zws = (float*)d_ws;          // needs B*8*4 = 256 KiB

    int B = in_sizes[0] / NQ;           // 8192

    qcircuit_z<<<(B + 7) / 8, 512, 0, stream>>>(x, qw, zws, B);
    qmlp2<<<(B + 15) / 16, 256, 0, stream>>>(zws, W1, b1, W2, b2, out, B);
}